// Round 15
// baseline (336.027 us; speedup 1.0000x reference)
//
#include <hip/hip_runtime.h>

#define NOUT1 12
#define NOUT2 15
#define NBINS 4000
#define NFEAT 6
#define NT    500
#define NTPAD 512
#define NEVT  64
#define LOG2E 1.4426950408889634f
#define LN2   0.6931471805599453f

typedef __attribute__((ext_vector_type(4))) _Float16 f16x4;
typedef __attribute__((ext_vector_type(4))) float f32x4;

__device__ __forceinline__ float leaky(float s) {
    return s >= 0.0f ? s : 0.01f * s;
}

// d' = d*log2e (scale folded into W3/b3 upstream).
// softplus(d)/ln2 = max(d',0) + log2(1+2^(-|d'|)); cubic minimax, |err|~1.2e-3 ln.
// Pure scalar: 1 trans (neg+abs fold into input modifier) + 5 VALU, no packing moves.
__device__ __forceinline__ void sp1(float d, float& am, float& ap) {
    float u = __builtin_amdgcn_exp2f(-__builtin_fabsf(d));
    am += fmaxf(d, 0.0f);
    float q = fmaf(u, 0.175167f, -0.602758f);
    q = fmaf(u, q, 1.428718f);
    ap = fmaf(u, q, ap);
}

__device__ __forceinline__ unsigned short f16bits(float v) {
    return __builtin_bit_cast(unsigned short, (_Float16)v);
}

// ---- one track's h2 row as 16 f16 (slot15 = 1.0 bias carrier) ----
__device__ __forceinline__ void h2_row_f16(
    const float* __restrict__ x, int e, int t,
    const float* __restrict__ W1, const float* __restrict__ b1,
    const float* __restrict__ W2, const float* __restrict__ b2,
    unsigned int packed[8])
{
    float f[NFEAT];
    #pragma unroll
    for (int i = 0; i < NFEAT; ++i)
        f[i] = x[e * NFEAT * NT + i * NT + t];   // x is (E, F, T)

    float h1[NOUT1];
    #pragma unroll
    for (int o = 0; o < NOUT1; ++o) {
        float s = b1[o];
        #pragma unroll
        for (int i = 0; i < NFEAT; ++i)
            s = fmaf(f[i], W1[o * NFEAT + i], s);
        h1[o] = leaky(s);
    }

    unsigned short hf[16];
    #pragma unroll
    for (int o = 0; o < NOUT2; ++o) {
        float s = b2[o];
        #pragma unroll
        for (int i = 0; i < NOUT1; ++i)
            s = fmaf(h1[i], W2[o * NOUT1 + i], s);
        hf[o] = f16bits(leaky(s));
    }
    hf[15] = f16bits(1.0f);   // bias carrier slot
    #pragma unroll
    for (int j = 0; j < 8; ++j)
        packed[j] = (unsigned int)hf[2*j] | ((unsigned int)hf[2*j+1] << 16);
}

// ---- Kernel 1: merged prep. Blocks 0..127: h2 -> wsA; 128..143: W3 -> wsB ----
__global__ __launch_bounds__(256) void prep(
    const float* __restrict__ x,
    const float* __restrict__ W1, const float* __restrict__ b1,
    const float* __restrict__ W2, const float* __restrict__ b2,
    const float* __restrict__ W3, const float* __restrict__ b3,
    uint2* __restrict__ wsA, uint2* __restrict__ wsB)
{
    const int b = blockIdx.x;
    if (b < 2 * NEVT) {
        const int e = b >> 1;
        const int t = (b & 1) * 256 + threadIdx.x;
        unsigned int packed[8];
        if (t < NT) {
            h2_row_f16(x, e, t, W1, b1, W2, b2, packed);
        } else {
            #pragma unroll
            for (int j = 0; j < 8; ++j) packed[j] = 0;   // pad rows fully zero
        }
        uint2* dst = wsA + (size_t)e * 2048 + (t >> 4) * 64 + (t & 15);
        dst[0]  = make_uint2(packed[0], packed[1]);
        dst[16] = make_uint2(packed[2], packed[3]);
        dst[32] = make_uint2(packed[4], packed[5]);
        dst[48] = make_uint2(packed[6], packed[7]);
    } else {
        const int bin = (b - 2 * NEVT) * 256 + threadIdx.x;
        if (bin >= NBINS) return;
        unsigned short wf[16];
        #pragma unroll
        for (int k = 0; k < NOUT2; ++k)
            wf[k] = f16bits(W3[bin * NOUT2 + k] * LOG2E);
        wf[15] = f16bits(b3[bin] * LOG2E);
        uint2* dst = wsB + (size_t)bin * 4;
        #pragma unroll
        for (int g = 0; g < 4; ++g)
            dst[g] = make_uint2((unsigned int)wf[4*g] | ((unsigned int)wf[4*g+1] << 16),
                                (unsigned int)wf[4*g+2] | ((unsigned int)wf[4*g+3] << 16));
    }
}

// ---- Kernel 2: 32 bins x 512 tracks per wave; 1 ds_read feeds 2 MFMAs ----
__global__ __launch_bounds__(512, 8) void kde_main(
    const uint2* __restrict__ wsA, const uint2* __restrict__ wsB,
    float* __restrict__ out)
{
    __shared__ uint2 h2lds[2048];   // 16 KB, [tile32][kg4][col16]
    const int tid   = threadIdx.x;
    const int chunk = blockIdx.x;   // 0..15 -> 256 bins each
    const int e     = blockIdx.y;

    {   // 16 KB identity copy, uint4-wide
        uint4* l4 = reinterpret_cast<uint4*>(h2lds);
        const uint4* g4 = reinterpret_cast<const uint4*>(wsA + (size_t)e * 2048);
        l4[tid]       = g4[tid];
        l4[tid + 512] = g4[tid + 512];
    }

    const int wid  = tid >> 6;
    const int lane = tid & 63;
    const int col  = lane & 15;
    const int kg   = lane >> 4;
    const int binbase = chunk * 256 + wid * 32;   // per-wave: 32 bins
    const int bi0 = binbase + col      < NBINS ? binbase + col      : NBINS - 1;
    const int bi1 = binbase + col + 16 < NBINS ? binbase + col + 16 : NBINS - 1;
    // two B fragments from the precomputed table (L2-resident, 128 KB)
    f16x4 Ba = __builtin_bit_cast(f16x4, wsB[(size_t)bi0 * 4 + kg]);
    f16x4 Bb = __builtin_bit_cast(f16x4, wsB[(size_t)bi1 * 4 + kg]);

    __syncthreads();
    if (binbase >= NBINS) return;   // wave-uniform exit

    const f32x4 zero4 = {0.0f, 0.0f, 0.0f, 0.0f};
    // 16 independent scalar accumulator chains (max-part + poly-part per slot)
    float amA0 = 0.f, amA1 = 0.f, amA2 = 0.f, amA3 = 0.f;
    float apA0 = 0.f, apA1 = 0.f, apA2 = 0.f, apA3 = 0.f;
    float amB0 = 0.f, amB1 = 0.f, amB2 = 0.f, amB3 = 0.f;
    float apB0 = 0.f, apB1 = 0.f, apB2 = 0.f, apB3 = 0.f;
    const uint2* ap_ = h2lds + kg * 16 + col;

    #define TILE_BODY(areg)                                                          \
        {                                                                            \
            f16x4 av = __builtin_bit_cast(f16x4, areg);                              \
            f32x4 ca = __builtin_amdgcn_mfma_f32_16x16x16f16(av, Ba, zero4, 0, 0, 0);\
            f32x4 cb = __builtin_amdgcn_mfma_f32_16x16x16f16(av, Bb, zero4, 0, 0, 0);\
            sp1(ca[0], amA0, apA0); sp1(ca[1], amA1, apA1);                          \
            sp1(ca[2], amA2, apA2); sp1(ca[3], amA3, apA3);                          \
            sp1(cb[0], amB0, apB0); sp1(cb[1], amB1, apB1);                          \
            sp1(cb[2], amB2, apB2); sp1(cb[3], amB3, apB3);                          \
        }

    // distance-4 LDS prefetch ring; full unroll keeps all indices static
    uint2 A[4];
    A[0] = ap_[0 * 64];
    A[1] = ap_[1 * 64];
    A[2] = ap_[2 * 64];
    A[3] = ap_[3 * 64];

    #pragma unroll
    for (int g = 0; g < 31; ++g) {
        uint2 cur = A[g & 3];
        if (g + 4 < 32)
            A[g & 3] = ap_[(g + 4) * 64];
        TILE_BODY(cur)
    }
    {   // tile 31: tracks 496..511; C row = kg*4+reg -> only kg==0 (496..499) real
        f16x4 av = __builtin_bit_cast(f16x4, A[3]);
        f32x4 ca = __builtin_amdgcn_mfma_f32_16x16x16f16(av, Ba, zero4, 0, 0, 0);
        f32x4 cb = __builtin_amdgcn_mfma_f32_16x16x16f16(av, Bb, zero4, 0, 0, 0);
        if (kg == 0) {
            sp1(ca[0], amA0, apA0); sp1(ca[1], amA1, apA1);
            sp1(ca[2], amA2, apA2); sp1(ca[3], amA3, apA3);
            sp1(cb[0], amB0, apB0); sp1(cb[1], amB1, apB1);
            sp1(cb[2], amB2, apB2); sp1(cb[3], amB3, apB3);
        }
    }
    #undef TILE_BODY

    float sumA = ((amA0 + amA1) + (amA2 + amA3)) + ((apA0 + apA1) + (apA2 + apA3));
    float sumB = ((amB0 + amB1) + (amB2 + amB3)) + ((apB0 + apB1) + (apB2 + apB3));
    sumA += __shfl_xor(sumA, 16);
    sumA += __shfl_xor(sumA, 32);
    sumB += __shfl_xor(sumB, 16);
    sumB += __shfl_xor(sumB, 32);
    if (lane < 16) {
        out[e * NBINS + binbase + col]      = sumA * LN2;
        out[e * NBINS + binbase + col + 16] = sumB * LN2;
    }
}

// ---- Fallback: fused single kernel (if ws too small) ----
__global__ __launch_bounds__(512, 2) void kde_fused(
    const float* __restrict__ x,
    const float* __restrict__ W1, const float* __restrict__ b1,
    const float* __restrict__ W2, const float* __restrict__ b2,
    const float* __restrict__ W3, const float* __restrict__ b3,
    float* __restrict__ out)
{
    __shared__ uint2 h2lds[2048];
    const int tid   = threadIdx.x;
    const int chunk = blockIdx.x;
    const int e     = blockIdx.y;

    {
        unsigned int packed[8];
        if (tid < NT) {
            h2_row_f16(x, e, tid, W1, b1, W2, b2, packed);
        } else {
            #pragma unroll
            for (int j = 0; j < 8; ++j) packed[j] = 0;
        }
        uint2* dst = &h2lds[(tid >> 4) * 64 + (tid & 15)];
        dst[0]  = make_uint2(packed[0], packed[1]);
        dst[16] = make_uint2(packed[2], packed[3]);
        dst[32] = make_uint2(packed[4], packed[5]);
        dst[48] = make_uint2(packed[6], packed[7]);
    }

    const int wid  = tid >> 6;
    const int lane = tid & 63;
    const int col  = lane & 15;
    const int kg   = lane >> 4;
    const int binbase = chunk * 256 + wid * 32;
    const int bi0 = binbase + col      < NBINS ? binbase + col      : NBINS - 1;
    const int bi1 = binbase + col + 16 < NBINS ? binbase + col + 16 : NBINS - 1;
    f16x4 Ba, Bb;
    #pragma unroll
    for (int j = 0; j < 4; ++j) {
        const int kk = kg * 4 + j;
        Ba[j] = (_Float16)((kk < NOUT2) ? W3[bi0 * NOUT2 + kk] * LOG2E : b3[bi0] * LOG2E);
        Bb[j] = (_Float16)((kk < NOUT2) ? W3[bi1 * NOUT2 + kk] * LOG2E : b3[bi1] * LOG2E);
    }

    __syncthreads();
    if (binbase >= NBINS) return;

    const f32x4 zero4 = {0.0f, 0.0f, 0.0f, 0.0f};
    float amA = 0.f, apA = 0.f, amB = 0.f, apB = 0.f;
    const uint2* ap_ = h2lds + kg * 16 + col;

    #pragma unroll
    for (int g = 0; g < 32; ++g) {
        f16x4 av = __builtin_bit_cast(f16x4, ap_[g * 64]);
        f32x4 ca = __builtin_amdgcn_mfma_f32_16x16x16f16(av, Ba, zero4, 0, 0, 0);
        f32x4 cb = __builtin_amdgcn_mfma_f32_16x16x16f16(av, Bb, zero4, 0, 0, 0);
        if (g == 31 && kg != 0) break;
        #pragma unroll
        for (int i = 0; i < 4; ++i) {
            sp1(ca[i], amA, apA);
            sp1(cb[i], amB, apB);
        }
    }

    float sumA = amA + apA;
    float sumB = amB + apB;
    sumA += __shfl_xor(sumA, 16);
    sumA += __shfl_xor(sumA, 32);
    sumB += __shfl_xor(sumB, 16);
    sumB += __shfl_xor(sumB, 32);
    if (lane < 16) {
        out[e * NBINS + binbase + col]      = sumA * LN2;
        out[e * NBINS + binbase + col + 16] = sumB * LN2;
    }
}

extern "C" void kernel_launch(void* const* d_in, const int* in_sizes, int n_in,
                              void* d_out, int out_size, void* d_ws, size_t ws_size,
                              hipStream_t stream) {
    const float* x  = (const float*)d_in[0];
    const float* W1 = (const float*)d_in[1];
    const float* b1 = (const float*)d_in[2];
    const float* W2 = (const float*)d_in[3];
    const float* b2 = (const float*)d_in[4];
    const float* W3 = (const float*)d_in[5];
    const float* b3 = (const float*)d_in[6];
    float* out = (float*)d_out;

    // ws layout: wsA = 64 events x 16 KB (1 MB); wsB = 4000 x 32 B (128 KB)
    const size_t wsA_bytes = (size_t)NEVT * 2048 * sizeof(uint2);
    const size_t wsB_bytes = (size_t)NBINS * 4 * sizeof(uint2);
    if (ws_size >= wsA_bytes + wsB_bytes) {
        uint2* wsA = (uint2*)d_ws;
        uint2* wsB = (uint2*)((char*)d_ws + wsA_bytes);
        prep<<<2 * NEVT + (NBINS + 255) / 256, 256, 0, stream>>>(
            x, W1, b1, W2, b2, W3, b3, wsA, wsB);
        dim3 grid(16, NEVT);
        kde_main<<<grid, 512, 0, stream>>>(wsA, wsB, out);
    } else {
        dim3 grid(16, NEVT);
        kde_fused<<<grid, 512, 0, stream>>>(x, W1, b1, W2, b2, W3, b3, out);
    }
}

// Round 16
// 36.138 us; speedup vs baseline: 9.2985x; 9.2985x over previous
//
#include <hip/hip_runtime.h>

#define NOUT1 12
#define NOUT2 15
#define NBINS 4000
#define NFEAT 6
#define NT    500
#define NTPAD 512
#define NEVT  64
#define LOG2E 1.4426950408889634f
#define LN2   0.6931471805599453f

typedef __attribute__((ext_vector_type(4))) _Float16 f16x4;
typedef __attribute__((ext_vector_type(4))) float f32x4;
typedef __attribute__((ext_vector_type(2))) float f32x2;

__device__ __forceinline__ float leaky(float s) {
    return s >= 0.0f ? s : 0.01f * s;
}

// d' = d*log2e (scale folded into W3/b3 upstream).
// softplus(d)/ln2 = max(d',0) + log2(1+2^(-|d'|)); cubic minimax, |err|~1.2e-3 ln.
__device__ __forceinline__ void sp2_acc(f32x2 d, f32x2& acc) {
    f32x2 u;
    u.x = __builtin_amdgcn_exp2f(-__builtin_fabsf(d.x));
    u.y = __builtin_amdgcn_exp2f(-__builtin_fabsf(d.y));
    acc += __builtin_elementwise_max(d, (f32x2)0.0f);
    f32x2 q = __builtin_elementwise_fma(u, (f32x2)0.175167f, (f32x2)(-0.602758f));
    q = __builtin_elementwise_fma(u, q, (f32x2)1.428718f);
    acc = __builtin_elementwise_fma(u, q, acc);
}

__device__ __forceinline__ unsigned short f16bits(float v) {
    return __builtin_bit_cast(unsigned short, (_Float16)v);
}

// ---- one track's h2 row as 16 f16 (slot15 = 1.0 bias carrier) ----
__device__ __forceinline__ void h2_row_f16(
    const float* __restrict__ x, int e, int t,
    const float* __restrict__ W1, const float* __restrict__ b1,
    const float* __restrict__ W2, const float* __restrict__ b2,
    unsigned int packed[8])
{
    float f[NFEAT];
    #pragma unroll
    for (int i = 0; i < NFEAT; ++i)
        f[i] = x[e * NFEAT * NT + i * NT + t];   // x is (E, F, T)

    float h1[NOUT1];
    #pragma unroll
    for (int o = 0; o < NOUT1; ++o) {
        float s = b1[o];
        #pragma unroll
        for (int i = 0; i < NFEAT; ++i)
            s = fmaf(f[i], W1[o * NFEAT + i], s);
        h1[o] = leaky(s);
    }

    unsigned short hf[16];
    #pragma unroll
    for (int o = 0; o < NOUT2; ++o) {
        float s = b2[o];
        #pragma unroll
        for (int i = 0; i < NOUT1; ++i)
            s = fmaf(h1[i], W2[o * NOUT1 + i], s);
        hf[o] = f16bits(leaky(s));
    }
    hf[15] = f16bits(1.0f);   // bias carrier slot
    #pragma unroll
    for (int j = 0; j < 8; ++j)
        packed[j] = (unsigned int)hf[2*j] | ((unsigned int)hf[2*j+1] << 16);
}

// ---- Kernel 1: merged prep. Blocks 0..127: h2 -> wsA; 128..143: W3 -> wsB ----
__global__ __launch_bounds__(256) void prep(
    const float* __restrict__ x,
    const float* __restrict__ W1, const float* __restrict__ b1,
    const float* __restrict__ W2, const float* __restrict__ b2,
    const float* __restrict__ W3, const float* __restrict__ b3,
    uint2* __restrict__ wsA, uint2* __restrict__ wsB)
{
    const int b = blockIdx.x;
    if (b < 2 * NEVT) {
        const int e = b >> 1;
        const int t = (b & 1) * 256 + threadIdx.x;
        unsigned int packed[8];
        if (t < NT) {
            h2_row_f16(x, e, t, W1, b1, W2, b2, packed);
        } else {
            #pragma unroll
            for (int j = 0; j < 8; ++j) packed[j] = 0;   // pad rows fully zero
        }
        uint2* dst = wsA + (size_t)e * 2048 + (t >> 4) * 64 + (t & 15);
        dst[0]  = make_uint2(packed[0], packed[1]);
        dst[16] = make_uint2(packed[2], packed[3]);
        dst[32] = make_uint2(packed[4], packed[5]);
        dst[48] = make_uint2(packed[6], packed[7]);
    } else {
        const int bin = (b - 2 * NEVT) * 256 + threadIdx.x;
        if (bin >= NBINS) return;
        unsigned short wf[16];
        #pragma unroll
        for (int k = 0; k < NOUT2; ++k)
            wf[k] = f16bits(W3[bin * NOUT2 + k] * LOG2E);
        wf[15] = f16bits(b3[bin] * LOG2E);
        uint2* dst = wsB + (size_t)bin * 4;
        #pragma unroll
        for (int g = 0; g < 4; ++g)
            dst[g] = make_uint2((unsigned int)wf[4*g] | ((unsigned int)wf[4*g+1] << 16),
                                (unsigned int)wf[4*g+2] | ((unsigned int)wf[4*g+3] << 16));
    }
}

// ---- Kernel 2: 32 bins x 512 tracks per wave; 1 ds_read feeds 2 MFMAs ----
__global__ __launch_bounds__(512, 8) void kde_main(
    const uint2* __restrict__ wsA, const uint2* __restrict__ wsB,
    float* __restrict__ out)
{
    __shared__ uint2 h2lds[2048];   // 16 KB, [tile32][kg4][col16]
    const int tid   = threadIdx.x;
    const int chunk = blockIdx.x;   // 0..15 -> 256 bins each
    const int e     = blockIdx.y;

    {   // 16 KB identity copy, uint4-wide
        uint4* l4 = reinterpret_cast<uint4*>(h2lds);
        const uint4* g4 = reinterpret_cast<const uint4*>(wsA + (size_t)e * 2048);
        l4[tid]       = g4[tid];
        l4[tid + 512] = g4[tid + 512];
    }

    const int wid  = tid >> 6;
    const int lane = tid & 63;
    const int col  = lane & 15;
    const int kg   = lane >> 4;
    const int binbase = chunk * 256 + wid * 32;   // per-wave: 32 bins
    // active waves are fully valid (4000 % 32 == 0); clamp only for safety
    const int bi0 = binbase + col      < NBINS ? binbase + col      : NBINS - 1;
    const int bi1 = binbase + col + 16 < NBINS ? binbase + col + 16 : NBINS - 1;
    // two B fragments from the precomputed table (L2-resident, 128 KB)
    f16x4 Ba = __builtin_bit_cast(f16x4, wsB[(size_t)bi0 * 4 + kg]);
    f16x4 Bb = __builtin_bit_cast(f16x4, wsB[(size_t)bi1 * 4 + kg]);

    __syncthreads();
    if (binbase >= NBINS) return;   // wave-uniform exit

    const f32x4 zero4 = {0.0f, 0.0f, 0.0f, 0.0f};
    f32x2 accA0 = {0.f,0.f}, accA1 = accA0, accB0 = accA0, accB1 = accA0;
    const uint2* ap = h2lds + kg * 16 + col;

    #define TILE_BODY(areg)                                                          \
        {                                                                            \
            f16x4 av = __builtin_bit_cast(f16x4, areg);                              \
            f32x4 ca = __builtin_amdgcn_mfma_f32_16x16x16f16(av, Ba, zero4, 0, 0, 0);\
            f32x4 cb = __builtin_amdgcn_mfma_f32_16x16x16f16(av, Bb, zero4, 0, 0, 0);\
            f32x2 pa0 = {ca[0], ca[1]}, pa1 = {ca[2], ca[3]};                        \
            f32x2 pb0 = {cb[0], cb[1]}, pb1 = {cb[2], cb[3]};                        \
            sp2_acc(pa0, accA0); sp2_acc(pa1, accA1);                                \
            sp2_acc(pb0, accB0); sp2_acc(pb1, accB1);                                \
        }

    // distance-4 LDS prefetch ring; full unroll keeps all indices static
    uint2 A[4];
    A[0] = ap[0 * 64];
    A[1] = ap[1 * 64];
    A[2] = ap[2 * 64];
    A[3] = ap[3 * 64];

    #pragma unroll
    for (int g = 0; g < 31; ++g) {
        uint2 cur = A[g & 3];
        if (g + 4 < 32)
            A[g & 3] = ap[(g + 4) * 64];
        TILE_BODY(cur)
    }
    {   // tile 31: tracks 496..511; C row = kg*4+reg -> only kg==0 (496..499) real
        f16x4 av = __builtin_bit_cast(f16x4, A[3]);
        f32x4 ca = __builtin_amdgcn_mfma_f32_16x16x16f16(av, Ba, zero4, 0, 0, 0);
        f32x4 cb = __builtin_amdgcn_mfma_f32_16x16x16f16(av, Bb, zero4, 0, 0, 0);
        if (kg == 0) {
            f32x2 pa0 = {ca[0], ca[1]}, pa1 = {ca[2], ca[3]};
            f32x2 pb0 = {cb[0], cb[1]}, pb1 = {cb[2], cb[3]};
            sp2_acc(pa0, accA0); sp2_acc(pa1, accA1);
            sp2_acc(pb0, accB0); sp2_acc(pb1, accB1);
        }
    }
    #undef TILE_BODY

    f32x2 sA2 = accA0 + accA1;
    f32x2 sB2 = accB0 + accB1;
    float sumA = sA2.x + sA2.y;
    float sumB = sB2.x + sB2.y;
    sumA += __shfl_xor(sumA, 16);
    sumA += __shfl_xor(sumA, 32);
    sumB += __shfl_xor(sumB, 16);
    sumB += __shfl_xor(sumB, 32);
    if (lane < 16) {
        out[e * NBINS + binbase + col]      = sumA * LN2;
        out[e * NBINS + binbase + col + 16] = sumB * LN2;
    }
}

// ---- Fallback: fused single kernel (if ws too small) ----
__global__ __launch_bounds__(512, 2) void kde_fused(
    const float* __restrict__ x,
    const float* __restrict__ W1, const float* __restrict__ b1,
    const float* __restrict__ W2, const float* __restrict__ b2,
    const float* __restrict__ W3, const float* __restrict__ b3,
    float* __restrict__ out)
{
    __shared__ uint2 h2lds[2048];
    const int tid   = threadIdx.x;
    const int chunk = blockIdx.x;
    const int e     = blockIdx.y;

    {
        unsigned int packed[8];
        if (tid < NT) {
            h2_row_f16(x, e, tid, W1, b1, W2, b2, packed);
        } else {
            #pragma unroll
            for (int j = 0; j < 8; ++j) packed[j] = 0;
        }
        uint2* dst = &h2lds[(tid >> 4) * 64 + (tid & 15)];
        dst[0]  = make_uint2(packed[0], packed[1]);
        dst[16] = make_uint2(packed[2], packed[3]);
        dst[32] = make_uint2(packed[4], packed[5]);
        dst[48] = make_uint2(packed[6], packed[7]);
    }

    const int wid  = tid >> 6;
    const int lane = tid & 63;
    const int col  = lane & 15;
    const int kg   = lane >> 4;
    const int binbase = chunk * 256 + wid * 32;
    const int bi0 = binbase + col      < NBINS ? binbase + col      : NBINS - 1;
    const int bi1 = binbase + col + 16 < NBINS ? binbase + col + 16 : NBINS - 1;
    f16x4 Ba, Bb;
    #pragma unroll
    for (int j = 0; j < 4; ++j) {
        const int kk = kg * 4 + j;
        Ba[j] = (_Float16)((kk < NOUT2) ? W3[bi0 * NOUT2 + kk] * LOG2E : b3[bi0] * LOG2E);
        Bb[j] = (_Float16)((kk < NOUT2) ? W3[bi1 * NOUT2 + kk] * LOG2E : b3[bi1] * LOG2E);
    }

    __syncthreads();
    if (binbase >= NBINS) return;

    const f32x4 zero4 = {0.0f, 0.0f, 0.0f, 0.0f};
    f32x2 accA0 = {0.f,0.f}, accA1 = accA0, accB0 = accA0, accB1 = accA0;
    const uint2* ap = h2lds + kg * 16 + col;

    #pragma unroll
    for (int g = 0; g < 32; ++g) {
        f16x4 av = __builtin_bit_cast(f16x4, ap[g * 64]);
        f32x4 ca = __builtin_amdgcn_mfma_f32_16x16x16f16(av, Ba, zero4, 0, 0, 0);
        f32x4 cb = __builtin_amdgcn_mfma_f32_16x16x16f16(av, Bb, zero4, 0, 0, 0);
        if (g == 31 && kg != 0) break;
        f32x2 pa0 = {ca[0], ca[1]}, pa1 = {ca[2], ca[3]};
        f32x2 pb0 = {cb[0], cb[1]}, pb1 = {cb[2], cb[3]};
        sp2_acc(pa0, accA0); sp2_acc(pa1, accA1);
        sp2_acc(pb0, accB0); sp2_acc(pb1, accB1);
    }

    f32x2 sA2 = accA0 + accA1;
    f32x2 sB2 = accB0 + accB1;
    float sumA = sA2.x + sA2.y;
    float sumB = sB2.x + sB2.y;
    sumA += __shfl_xor(sumA, 16);
    sumA += __shfl_xor(sumA, 32);
    sumB += __shfl_xor(sumB, 16);
    sumB += __shfl_xor(sumB, 32);
    if (lane < 16) {
        out[e * NBINS + binbase + col]      = sumA * LN2;
        out[e * NBINS + binbase + col + 16] = sumB * LN2;
    }
}

extern "C" void kernel_launch(void* const* d_in, const int* in_sizes, int n_in,
                              void* d_out, int out_size, void* d_ws, size_t ws_size,
                              hipStream_t stream) {
    const float* x  = (const float*)d_in[0];
    const float* W1 = (const float*)d_in[1];
    const float* b1 = (const float*)d_in[2];
    const float* W2 = (const float*)d_in[3];
    const float* b2 = (const float*)d_in[4];
    const float* W3 = (const float*)d_in[5];
    const float* b3 = (const float*)d_in[6];
    float* out = (float*)d_out;

    // ws layout: wsA = 64 events x 16 KB (1 MB); wsB = 4000 x 32 B (128 KB)
    const size_t wsA_bytes = (size_t)NEVT * 2048 * sizeof(uint2);
    const size_t wsB_bytes = (size_t)NBINS * 4 * sizeof(uint2);
    if (ws_size >= wsA_bytes + wsB_bytes) {
        uint2* wsA = (uint2*)d_ws;
        uint2* wsB = (uint2*)((char*)d_ws + wsA_bytes);
        prep<<<2 * NEVT + (NBINS + 255) / 256, 256, 0, stream>>>(
            x, W1, b1, W2, b2, W3, b3, wsA, wsB);
        dim3 grid(16, NEVT);
        kde_main<<<grid, 512, 0, stream>>>(wsA, wsB, out);
    } else {
        dim3 grid(16, NEVT);
        kde_fused<<<grid, 512, 0, stream>>>(x, W1, b1, W2, b2, W3, b3, out);
    }
}